// Round 7
// baseline (19.248 us; speedup 1.0000x reference)
//
#include <hip/hip_runtime.h>

// out[i] = P(x[i]) / (|x[i]*Q(x[i])| + 1), packed Horner h={num,den}.
//
// R6 diagnosis: true time ~11.7us == compute floor (6.7us: 504 pk_fma x 4cyc)
// + memory floor (5.3us: 33.5MB @ 6.3TB/s) SERIALIZED. Single-tile-per-wave
// structure = [load; long dependent compute; store] in lockstep across all
// waves -> HBM phase cannot hide under VALU phase.
//
// Fix: 2 grid-stride tiles per thread with prefetch: issue tile t+1's loads
// (independent VGPRs, no wait) before computing tile t. Compute ~2000cyc >>
// HBM latency ~900cyc -> memory fully hidden, floor = max(6.7, 5.3) = 6.7us.

typedef float v2f __attribute__((ext_vector_type(2)));

#define EPT   8
#define TILES 2

__global__ __launch_bounds__(256) void rationals_kernel(
    const float* __restrict__ x,
    const float* __restrict__ coeff,
    float* __restrict__ out, int N) {
    const int tid    = blockIdx.x * blockDim.x + threadIdx.x;
    const int stride = gridDim.x * blockDim.x * EPT;  // elements per grid pass
    int idx = tid * EPT;

    const float cn_top = coeff[63];
    const float cd_top = coeff[127];

    // prefetch tile 0
    float4 na = *reinterpret_cast<const float4*>(x + idx);
    float4 nb = *reinterpret_cast<const float4*>(x + idx + 4);

#pragma unroll
    for (int t = 0; t < TILES; ++t) {
        const float4 xa = na, xb = nb;
        const int cur = idx;
        idx += stride;
        if (t + 1 < TILES) {  // prefetch next tile before computing this one
            na = *reinterpret_cast<const float4*>(x + idx);
            nb = *reinterpret_cast<const float4*>(x + idx + 4);
        }

        float xs[EPT] = {xa.x, xa.y, xa.z, xa.w, xb.x, xb.y, xb.z, xb.w};
        v2f xx[EPT], h[EPT];
#pragma unroll
        for (int j = 0; j < EPT; ++j) {
            xx[j] = (v2f){xs[j], xs[j]};
            h[j]  = (v2f){cn_top, cd_top};
        }

#pragma unroll
        for (int p = 62; p >= 0; --p) {
            v2f c2 = {coeff[p], coeff[64 + p]};  // wave-uniform pair
#pragma unroll
            for (int j = 0; j < EPT; ++j)
                h[j] = __builtin_elementwise_fma(h[j], xx[j], c2);
        }

        float o[EPT];
#pragma unroll
        for (int j = 0; j < EPT; ++j) {
            float den = h[j].y * xs[j];          // exponents 1..64
            o[j] = h[j].x * __builtin_amdgcn_rcpf(fabsf(den) + 1.0f);
        }
        *reinterpret_cast<float4*>(out + cur)     = (float4){o[0], o[1], o[2], o[3]};
        *reinterpret_cast<float4*>(out + cur + 4) = (float4){o[4], o[5], o[6], o[7]};
    }
}

extern "C" void kernel_launch(void* const* d_in, const int* in_sizes, int n_in,
                              void* d_out, int out_size, void* d_ws, size_t ws_size,
                              hipStream_t stream) {
    const float* x     = (const float*)d_in[0];
    const float* coeff = (const float*)d_in[1];
    float* out = (float*)d_out;
    int N = in_sizes[0];  // 4194304 = 256 * 8 * 2 * 1024 exactly

    int threads = 256;
    int elems_per_block = threads * EPT * TILES;
    int blocks = (N + elems_per_block - 1) / elems_per_block;  // 1024
    rationals_kernel<<<blocks, threads, 0, stream>>>(x, coeff, out, N);
}

// Round 8
// 17.100 us; speedup vs baseline: 1.1256x; 1.1256x over previous
//
#include <hip/hip_runtime.h>

// out[i] = P(x[i]) / (|x[i]*Q(x[i])| + 1)
//
// R7 diagnosis: plateau = compute-wall 10.1us (vs 7.2us pure issue) -- ~30%
// VALU bubbles from dep-latency: scheduler serializes to ~2 live Horner
// chains (R5: VGPR=20), each 63 DEPENDENT pk_fmas (issue 4cyc, dep ~8cyc).
//
// Fix: even/odd (Estrin) split -- P(x) = Pe(x^2) + x*Po(x^2). Two independent
// depth-31 packed chains per element; even fully serialized per-element, the
// he/ho alternation puts 8 issue-cycles between dependent steps -> latency
// covered structurally. Same FMA count. No scheduling fences.
//
// Packing: he = {Pe,Qe}, ho = {Po,Qo} in v2f; combine = pk_fma(ho,{x,x},he)
// -> {P,Q}; den = x*Q; out = P * rcp(|den|+1). rcp ok: den>=1 in magnitude+1,
// rel err ~1e-6 << threshold 0.4275.

typedef float v2f __attribute__((ext_vector_type(2)));

#define EPT 8

__global__ __launch_bounds__(256) void rationals_kernel(
    const float* __restrict__ x,
    const float* __restrict__ coeff,
    float* __restrict__ out, int N) {
    int idx = (blockIdx.x * blockDim.x + threadIdx.x) * EPT;
    if (idx >= N) return;

    float4 xa = *reinterpret_cast<const float4*>(x + idx);
    float4 xb = *reinterpret_cast<const float4*>(x + idx + 4);
    float xs[EPT] = {xa.x, xa.y, xa.z, xa.w, xb.x, xb.y, xb.z, xb.w};

    // top coefficients: even chain ends at p=62, odd at p=63
    const float ce_n = coeff[62],  co_n = coeff[63];
    const float ce_d = coeff[126], cd_o = coeff[127];

    v2f yy[EPT], he[EPT], ho[EPT];
#pragma unroll
    for (int j = 0; j < EPT; ++j) {
        float y = xs[j] * xs[j];
        yy[j] = (v2f){y, y};
        he[j] = (v2f){ce_n, ce_d};
        ho[j] = (v2f){co_n, cd_o};
    }

    // 31 steps down each chain: even coeffs 60,58,...,0; odd 61,59,...,1
#pragma unroll
    for (int p = 30; p >= 0; --p) {
        v2f ce = {coeff[2 * p],     coeff[64 + 2 * p]};      // wave-uniform
        v2f co = {coeff[2 * p + 1], coeff[64 + 2 * p + 1]};
#pragma unroll
        for (int j = 0; j < EPT; ++j) {
            he[j] = __builtin_elementwise_fma(he[j], yy[j], ce);
            ho[j] = __builtin_elementwise_fma(ho[j], yy[j], co);
        }
    }

    float o[EPT];
#pragma unroll
    for (int j = 0; j < EPT; ++j) {
        v2f xxj = (v2f){xs[j], xs[j]};
        v2f pq  = __builtin_elementwise_fma(ho[j], xxj, he[j]);  // {P, Q}
        float den = pq.y * xs[j];                                 // exps 1..64
        o[j] = pq.x * __builtin_amdgcn_rcpf(fabsf(den) + 1.0f);
    }
    *reinterpret_cast<float4*>(out + idx)     = (float4){o[0], o[1], o[2], o[3]};
    *reinterpret_cast<float4*>(out + idx + 4) = (float4){o[4], o[5], o[6], o[7]};
}

extern "C" void kernel_launch(void* const* d_in, const int* in_sizes, int n_in,
                              void* d_out, int out_size, void* d_ws, size_t ws_size,
                              hipStream_t stream) {
    const float* x     = (const float*)d_in[0];
    const float* coeff = (const float*)d_in[1];
    float* out = (float*)d_out;
    int N = in_sizes[0];  // 4194304, divisible by EPT

    int threads = 256;
    int elems_per_block = threads * EPT;
    int blocks = (N + elems_per_block - 1) / elems_per_block;  // 2048
    rationals_kernel<<<blocks, threads, 0, stream>>>(x, coeff, out, N);
}